// Round 8
// baseline (1138.177 us; speedup 1.0000x reference)
//
#include <hip/hip_runtime.h>
#include <math.h>

#define NB 32
#define NN 4096
#define DIN 768
#define DS 256
#define KS 8

typedef short s8v __attribute__((ext_vector_type(8)));
typedef float f4v __attribute__((ext_vector_type(4)));

__device__ __forceinline__ short f2bf(float f) {
    unsigned u = __builtin_bit_cast(unsigned, f);
    u = (u + 0x7FFFu + ((u >> 16) & 1u)) >> 16;
    return (short)u;
}
__device__ __forceinline__ float bf2f(short s) {
    unsigned u = ((unsigned)(unsigned short)s) << 16;
    return __builtin_bit_cast(float, u);
}
__device__ __forceinline__ float gelu_exact(float x) {
    return 0.5f * x * (1.0f + erff(x * 0.70710678118654752f));
}

// ---- swizzle Wp, Wks, Wkt into MFMA B-fragment order (bf16) ----
__global__ __launch_bounds__(256) void prep_weights(const float* Wp, const float* Wks,
                                                    const float* Wkt, short* Wp_sw, short* Wk_sw) {
    int t = blockIdx.x * 256 + threadIdx.x;
    if (t < 24 * 16 * 64) {
        int s = t / (16 * 64), nt = (t / 64) % 16, l = t % 64;
        int q = l >> 4, m = l & 15;
        #pragma unroll
        for (int j = 0; j < 8; ++j)
            Wp_sw[t * 8 + j] = f2bf(Wp[(s * 32 + q * 8 + j) * 256 + nt * 16 + m]);
    } else if (t < 24 * 16 * 64 + 2 * 4 * 8 * 64) {
        int t2 = t - 24 * 16 * 64;
        int half = t2 / (4 * 8 * 64);
        int r = t2 % (4 * 8 * 64);
        int s = r / (8 * 64), nt = (r / 64) % 8, l = r % 64;
        int q = l >> 4, m = l & 15;
        const float* W = half ? Wkt : Wks;
        #pragma unroll
        for (int j = 0; j < 8; ++j)
            Wk_sw[t2 * 8 + j] = f2bf(W[(s * 32 + q * 8 + j) * 128 + nt * 16 + m]);
    }
}

// ---- big GEMM fused with feature pooling: 1024 blocks x 128 rows (R3-proven) ----
__global__ __launch_bounds__(256, 2) void gemm_in_ln(const float* feat, const short* Wp_sw,
                                                     const float* bp, const float* g,
                                                     const float* bb, short* inputs_bf,
                                                     float* ppart) {
    __shared__ short Als[128 * 40];
    __shared__ short Bls[16 * 64 * 8];
    __shared__ float pool_ls[4][768];
    int tid = threadIdx.x;
    int wave = tid >> 6, lane = tid & 63, q = lane >> 4, m = lane & 15;
    long rowblk = (long)blockIdx.x * 128;
    f4v acc[2][16];
    #pragma unroll
    for (int rg = 0; rg < 2; ++rg)
        #pragma unroll
        for (int i = 0; i < 16; ++i) acc[rg][i] = (f4v){0, 0, 0, 0};
    for (int i = tid; i < 4 * 768; i += 256) (&pool_ls[0][0])[i] = 0.0f;
    __syncthreads();
    for (int s = 0; s < 24; ++s) {
        float4 v[4];
        #pragma unroll
        for (int p = 0; p < 4; ++p) {
            int idx = p * 256 + tid;
            int r = idx >> 3, cj = (idx & 7) * 4;
            v[p] = *(const float4*)(feat + (rowblk + r) * 768 + s * 32 + cj);
            short4 pk = make_short4(f2bf(v[p].x), f2bf(v[p].y), f2bf(v[p].z), f2bf(v[p].w));
            *(short4*)&Als[r * 40 + cj] = pk;
        }
        #pragma unroll
        for (int i = 0; i < 4; ++i) {
            int wb = i * 256 + wave * 64;
            __builtin_amdgcn_global_load_lds(
                (const __attribute__((address_space(1))) void*)(Wp_sw + (size_t)s * 8192 +
                                                               (size_t)(wb + lane) * 8),
                (__attribute__((address_space(3))) void*)&Bls[wb * 8], 16, 0, 0);
        }
        __syncthreads();
        {
            float px = v[0].x + v[1].x + v[2].x + v[3].x;
            float py = v[0].y + v[1].y + v[2].y + v[3].y;
            float pz = v[0].z + v[1].z + v[2].z + v[3].z;
            float pw = v[0].w + v[1].w + v[2].w + v[3].w;
            #pragma unroll
            for (int off = 8; off <= 32; off <<= 1) {
                px += __shfl_xor(px, off, 64);
                py += __shfl_xor(py, off, 64);
                pz += __shfl_xor(pz, off, 64);
                pw += __shfl_xor(pw, off, 64);
            }
            if (lane < 8) {
                int col = s * 32 + lane * 4;
                pool_ls[wave][col] += px;
                pool_ls[wave][col + 1] += py;
                pool_ls[wave][col + 2] += pz;
                pool_ls[wave][col + 3] += pw;
            }
        }
        s8v a0 = *(const s8v*)&Als[(wave * 32 + m) * 40 + q * 8];
        s8v a1 = *(const s8v*)&Als[(wave * 32 + 16 + m) * 40 + q * 8];
        #pragma unroll
        for (int nt = 0; nt < 16; ++nt) {
            s8v bf = *(const s8v*)&Bls[(nt * 64 + lane) * 8];
            acc[0][nt] = __builtin_amdgcn_mfma_f32_16x16x32_bf16(a0, bf, acc[0][nt], 0, 0, 0);
            acc[1][nt] = __builtin_amdgcn_mfma_f32_16x16x32_bf16(a1, bf, acc[1][nt], 0, 0, 0);
        }
        __syncthreads();
    }
    #pragma unroll
    for (int rg = 0; rg < 2; ++rg) {
        #pragma unroll
        for (int nt = 0; nt < 16; ++nt) {
            float bpv = bp[nt * 16 + m];
            #pragma unroll
            for (int r = 0; r < 4; ++r) acc[rg][nt][r] += bpv;
        }
        #pragma unroll
        for (int r = 0; r < 4; ++r) {
            float sm = 0, sq = 0;
            #pragma unroll
            for (int nt = 0; nt < 16; ++nt) { float vv = acc[rg][nt][r]; sm += vv; sq += vv * vv; }
            #pragma unroll
            for (int off = 1; off < 16; off <<= 1) {
                sm += __shfl_xor(sm, off, 16);
                sq += __shfl_xor(sq, off, 16);
            }
            float mean = sm * (1.0f / 256.0f);
            float var = sq * (1.0f / 256.0f) - mean * mean;
            float rstd = rsqrtf(var + 1e-5f);
            long grow = rowblk + wave * 32 + rg * 16 + q * 4 + r;
            #pragma unroll
            for (int nt = 0; nt < 16; ++nt) {
                int col = nt * 16 + m;
                float y = (acc[rg][nt][r] - mean) * rstd * g[col] + bb[col];
                inputs_bf[grow * 256 + col] = f2bf(y);
            }
        }
    }
    for (int d = tid; d < 768; d += 256) {
        ppart[(size_t)blockIdx.x * 768 + d] =
            pool_ls[0][d] + pool_ls[1][d] + pool_ls[2][d] + pool_ls[3][d];
    }
}

// ---- slot init MLP stage 1 ----
__global__ __launch_bounds__(256) void slots_hid(const float* ppart, const float* Wi1,
                                                 const float* bi1, float* hidb) {
    __shared__ float pool[768];
    int b = blockIdx.x, half = blockIdx.y, t = threadIdx.x;
    for (int i = 0; i < 3; ++i) {
        int d = t + i * 256;
        float s = 0;
        for (int c = 0; c < 32; ++c) s += ppart[(size_t)(b * 32 + c) * 768 + d];
        pool[d] = s * (1.0f / 4096.0f);
    }
    __syncthreads();
    int c = half * 256 + t;
    float acc = bi1[c];
    for (int j = 0; j < 768; ++j) acc += pool[j] * Wi1[j * 512 + c];
    hidb[b * 512 + c] = gelu_exact(acc);
}

// ---- slot init MLP stage 2 ----
__global__ __launch_bounds__(256) void slots_out(const float* hidb, const float* Wi2,
                                                 const float* bi2, float* slots) {
    __shared__ float hid[512];
    int b = blockIdx.x >> 3, sl = blockIdx.x & 7, t = threadIdx.x;
    hid[t] = hidb[b * 512 + t];
    hid[256 + t] = hidb[b * 512 + 256 + t];
    __syncthreads();
    int c = sl * 256 + t;
    float acc = bi2[c];
    for (int j = 0; j < 512; ++j) acc += hid[j] * Wi2[j * 2048 + c];
    slots[b * 2048 + c] = acc;
}

// ---- k_s / k_t GEMMs (R3-proven) ----
__global__ __launch_bounds__(256) void k_gemm(const short* inputs_bf, const short* Wk_sw,
                                              short* ksb, short* ktb) {
    int tid = threadIdx.x;
    int wave = tid >> 6, lane = tid & 63, q = lane >> 4, m = lane & 15;
    long rowblk = (long)blockIdx.x * 64;
    long arow = rowblk + wave * 16 + m;
    #pragma unroll
    for (int half = 0; half < 2; ++half) {
        f4v acc[8];
        #pragma unroll
        for (int i = 0; i < 8; ++i) acc[i] = (f4v){0, 0, 0, 0};
        const short* wkh = Wk_sw + half * 16384;
        #pragma unroll
        for (int s4 = 0; s4 < 4; ++s4) {
            s8v a = *(const s8v*)(inputs_bf + arow * 256 + half * 128 + s4 * 32 + q * 8);
            #pragma unroll
            for (int nt = 0; nt < 8; ++nt) {
                s8v bf = *(const s8v*)(wkh + ((s4 * 8 + nt) * 64 + lane) * 8);
                acc[nt] = __builtin_amdgcn_mfma_f32_16x16x32_bf16(a, bf, acc[nt], 0, 0, 0);
            }
        }
        short* out = half ? ktb : ksb;
        #pragma unroll
        for (int nt = 0; nt < 8; ++nt)
            #pragma unroll
            for (int r = 0; r < 4; ++r) {
                long grow = rowblk + wave * 16 + q * 4 + r;
                out[grow * 128 + nt * 16 + m] = f2bf(acc[nt][r]);
            }
    }
}

// ---- q projection (pre-loop only; later iterations get q from gru_kernel) ----
__global__ __launch_bounds__(256) void q_proj(const float* slots, const float* Wqs,
                                              const float* Wqt, float* qs, float* qt) {
    __shared__ float sl[1024];
    int b = blockIdx.x, half = blockIdx.y, t = threadIdx.x;
    for (int i = 0; i < 4; ++i) {
        int idx = i * 256 + t;
        int k = idx >> 7, d = idx & 127;
        sl[idx] = slots[(b * 8 + k) * 256 + half * 128 + d];
    }
    __syncthreads();
    const float* W = half ? Wqt : Wqs;
    float* out = half ? qt : qs;
    int d = t & 127;
    int k0 = (t >> 7) * 4;
    for (int k = k0; k < k0 + 4; ++k) {
        float acc = 0;
        for (int j = 0; j < 128; ++j) acc += sl[k * 128 + j] * W[j * 128 + d];
        out[(b * 8 + k) * 128 + d] = acc;
    }
}

// ---- logits + softmax(axis=k) + per-(b,k) partial N-sums. grid (8,32): 2 n per thread ----
__global__ __launch_bounds__(256) void attn_kernel(const short* ksb, const short* ktb,
                                                   const float* qs, const float* qt,
                                                   float* attn, float* Spart) {
    __shared__ float qls[1024], qlt[1024];
    __shared__ float red[32];
    int ntile = blockIdx.x, b = blockIdx.y, t = threadIdx.x;
    for (int i = 0; i < 4; ++i) {
        int idx = i * 256 + t;
        qls[idx] = qs[b * 1024 + idx];
        qlt[idx] = qt[b * 1024 + idx];
    }
    __syncthreads();
    long n0g = (long)b * 4096 + ntile * 512 + t;
    const short* krs0 = ksb + n0g * 128;
    const short* krt0 = ktb + n0g * 128;
    const short* krs1 = ksb + (n0g + 256) * 128;
    const short* krt1 = ktb + (n0g + 256) * 128;
    float accs0[8] = {0, 0, 0, 0, 0, 0, 0, 0};
    float acct0[8] = {0, 0, 0, 0, 0, 0, 0, 0};
    float accs1[8] = {0, 0, 0, 0, 0, 0, 0, 0};
    float acct1[8] = {0, 0, 0, 0, 0, 0, 0, 0};
    for (int c = 0; c < 16; ++c) {
        s8v vs0 = *(const s8v*)(krs0 + c * 8);
        s8v vt0 = *(const s8v*)(krt0 + c * 8);
        s8v vs1 = *(const s8v*)(krs1 + c * 8);
        s8v vt1 = *(const s8v*)(krt1 + c * 8);
        float fs0[8], ft0[8], fs1[8], ft1[8];
        #pragma unroll
        for (int j = 0; j < 8; ++j) {
            fs0[j] = bf2f(vs0[j]); ft0[j] = bf2f(vt0[j]);
            fs1[j] = bf2f(vs1[j]); ft1[j] = bf2f(vt1[j]);
        }
        #pragma unroll
        for (int k = 0; k < 8; ++k) {
            float as0 = 0, at0 = 0, as1 = 0, at1 = 0;
            #pragma unroll
            for (int j = 0; j < 8; ++j) {
                float qv_s = qls[k * 128 + c * 8 + j];
                float qv_t = qlt[k * 128 + c * 8 + j];
                as0 += qv_s * fs0[j]; as1 += qv_s * fs1[j];
                at0 += qv_t * ft0[j]; at1 += qv_t * ft1[j];
            }
            accs0[k] += as0; acct0[k] += at0;
            accs1[k] += as1; acct1[k] += at1;
        }
    }
    const float cs = 0.7f * 0.08838834764831845f;
    const float ct = 0.3f * 0.08838834764831845f;
    float lg0[8], lg1[8];
    float mx0 = -1e30f, mx1 = -1e30f;
    #pragma unroll
    for (int k = 0; k < 8; ++k) {
        lg0[k] = accs0[k] * cs + acct0[k] * ct; mx0 = fmaxf(mx0, lg0[k]);
        lg1[k] = accs1[k] * cs + acct1[k] * ct; mx1 = fmaxf(mx1, lg1[k]);
    }
    float se0 = 0, se1 = 0;
    #pragma unroll
    for (int k = 0; k < 8; ++k) {
        lg0[k] = expf(lg0[k] - mx0); se0 += lg0[k];
        lg1[k] = expf(lg1[k] - mx1); se1 += lg1[k];
    }
    float inv0 = 1.0f / se0, inv1 = 1.0f / se1;
    int nn0 = ntile * 512 + t;
    #pragma unroll
    for (int k = 0; k < 8; ++k) {
        float a0 = lg0[k] * inv0;
        float a1 = lg1[k] * inv1;
        attn[((long)(b * 8 + k)) * 4096 + nn0] = a0;
        attn[((long)(b * 8 + k)) * 4096 + nn0 + 256] = a1;
        lg0[k] = a0 + a1;
    }
    int lane = t & 63, wv = t >> 6;
    #pragma unroll
    for (int k = 0; k < 8; ++k) {
        float v = lg0[k];
        #pragma unroll
        for (int off = 1; off < 64; off <<= 1) v += __shfl_xor(v, off, 64);
        if (lane == 0) red[wv * 8 + k] = v;
    }
    __syncthreads();
    if (t < 8) {
        float s = red[t] + red[8 + t] + red[16 + t] + red[24 + t];
        Spart[(b * 8 + t) * 8 + ntile] = s;
    }
}

// ---- updates = attn_normed @ inputs. grid 256 (b x 2 dth x 4 nq), uint2 reads ----
__global__ __launch_bounds__(256) void updates_kernel(const short* inputs_bf, const float* attn,
                                                      const float* Spart, float* upart) {
    __shared__ unsigned inls[64 * 64];  // 64 n x 128 d (bf16 pairs), 16 KB
    __shared__ float atls[8 * 64];
    int bid = blockIdx.x;
    int b = bid >> 3, dth = (bid >> 2) & 1, nq = bid & 3;
    int t = threadIdx.x;
    int k = t >> 5, dp = t & 31;
    const float* spp = Spart + (b * 8 + k) * 8;
    float sp = ((spp[0] + spp[1]) + (spp[2] + spp[3])) +
               ((spp[4] + spp[5]) + (spp[6] + spp[7]));
    float rk = 1.0f / (sp + 1e-8f);
    float a0 = 0, a1 = 0, a2 = 0, a3 = 0;
    for (int ch = 0; ch < 16; ++ch) {
        long n0 = (long)nq * 1024 + ch * 64;
        #pragma unroll
        for (int p = 0; p < 4; ++p) {
            int idx = p * 256 + t;
            int rr = idx >> 4, cc = idx & 15;
            *(uint4*)&inls[rr * 64 + cc * 4] =
                *(const uint4*)(inputs_bf + ((long)b * 4096 + n0 + rr) * 256 + dth * 128 + cc * 8);
        }
        {
            int c2 = dp * 2;
            float2 av = *(const float2*)(attn + ((long)(b * 8 + k)) * 4096 + n0 + c2);
            atls[k * 64 + c2] = av.x * rk;
            atls[k * 64 + c2 + 1] = av.y * rk;
        }
        __syncthreads();
        #pragma unroll 16
        for (int j = 0; j < 64; ++j) {
            float a = atls[k * 64 + j];
            uint2 uu = *(const uint2*)&inls[j * 64 + dp * 2];
            a0 += a * bf2f((short)(uu.x & 0xFFFF));
            a1 += a * bf2f((short)(uu.x >> 16));
            a2 += a * bf2f((short)(uu.y & 0xFFFF));
            a3 += a * bf2f((short)(uu.y >> 16));
        }
        __syncthreads();
    }
    int bk = b * 8 + k;
    float* o = upart + ((long)(nq * 256 + bk)) * 256 + dth * 128 + dp * 4;
    o[0] = a0; o[1] = a1; o[2] = a2; o[3] = a3;
}

// ---- GRU + LN + MLP residual + (next-iter q | final out). grid 256 (b*8+k), 256 thr ----
__global__ __launch_bounds__(256) void gru_kernel(const float* upart, const float* W_ih,
                                                  const float* W_hh, const float* b_ih,
                                                  const float* b_hh, const float* ln_g,
                                                  const float* ln_b, const float* Wm1,
                                                  const float* bm1, const float* Wm2,
                                                  const float* bm2, float* slots,
                                                  const float* Wqs, const float* Wqt,
                                                  float* qs, float* qt, float* out, int final_it) {
    __shared__ float u[256], h[256], sn[256], hid[512];
    __shared__ float redA[4], redB[4];
    int bk = blockIdx.x, t = threadIdx.x;
    u[t] = upart[(0 * 256 + bk) * 256 + t] + upart[(1 * 256 + bk) * 256 + t] +
           upart[(2 * 256 + bk) * 256 + t] + upart[(3 * 256 + bk) * 256 + t];
    h[t] = slots[bk * 256 + t];
    __syncthreads();
    float xr = b_ih[t], xz = b_ih[256 + t], xn = b_ih[512 + t];
    float hr = b_hh[t], hz = b_hh[256 + t], hn = b_hh[512 + t];
    for (int j = 0; j < 256; ++j) {
        float uj = u[j], hj = h[j];
        const float* wi = W_ih + j * 768 + t;
        const float* wh = W_hh + j * 768 + t;
        xr += uj * wi[0]; xz += uj * wi[256]; xn += uj * wi[512];
        hr += hj * wh[0]; hz += hj * wh[256]; hn += hj * wh[512];
    }
    float rg = 1.0f / (1.0f + expf(-(xr + hr)));
    float zg = 1.0f / (1.0f + expf(-(xz + hz)));
    float ng = tanhf(xn + rg * hn);
    float hnew = (1.0f - zg) * ng + zg * h[t];
    float v1 = hnew, v2 = hnew * hnew;
    int lane = t & 63, wv = t >> 6;
    #pragma unroll
    for (int off = 1; off < 64; off <<= 1) {
        v1 += __shfl_xor(v1, off, 64);
        v2 += __shfl_xor(v2, off, 64);
    }
    if (lane == 0) { redA[wv] = v1; redB[wv] = v2; }
    __syncthreads();
    float sm = redA[0] + redA[1] + redA[2] + redA[3];
    float sq = redB[0] + redB[1] + redB[2] + redB[3];
    float mean = sm * (1.0f / 256.0f);
    float var = sq * (1.0f / 256.0f) - mean * mean;
    float rstd = rsqrtf(var + 1e-5f);
    sn[t] = (hnew - mean) * rstd * ln_g[t] + ln_b[t];
    __syncthreads();
    float m1 = bm1[t], m2 = bm1[256 + t];
    for (int j = 0; j < 256; ++j) {
        float s = sn[j];
        m1 += s * Wm1[j * 512 + t];
        m2 += s * Wm1[j * 512 + 256 + t];
    }
    hid[t] = gelu_exact(m1);
    hid[256 + t] = gelu_exact(m2);
    __syncthreads();
    float o = bm2[t];
    for (int j = 0; j < 512; ++j) o += hid[j] * Wm2[j * 256 + t];
    float v = hnew + o;
    slots[bk * 256 + t] = v;
    if (!final_it) {
        u[t] = v;
        __syncthreads();
        int half = t >> 7, d = t & 127;
        const float* W = half ? Wqt : Wqs;
        float qa = 0;
        for (int j = 0; j < 128; ++j) qa += u[half * 128 + j] * W[j * 128 + d];
        (half ? qt : qs)[bk * 128 + d] = qa;
    } else {
        out[bk * 256 + t] = v;
        if (t < 128) out[1114112 + bk * 128 + t] = v;
        else out[1114112 + 32768 + bk * 128 + (t - 128)] = v;
    }
}

extern "C" void kernel_launch(void* const* d_in, const int* in_sizes, int n_in,
                              void* d_out, int out_size, void* d_ws, size_t ws_size,
                              hipStream_t stream) {
    const float* feat    = (const float*)d_in[0];
    const float* Wi1     = (const float*)d_in[1];
    const float* bi1     = (const float*)d_in[2];
    const float* Wi2     = (const float*)d_in[3];
    const float* bi2     = (const float*)d_in[4];
    const float* Wp      = (const float*)d_in[5];
    const float* bp      = (const float*)d_in[6];
    const float* ln_in_g = (const float*)d_in[7];
    const float* ln_in_b = (const float*)d_in[8];
    const float* Wqs     = (const float*)d_in[9];
    const float* Wks     = (const float*)d_in[10];
    const float* Wqt     = (const float*)d_in[11];
    const float* Wkt     = (const float*)d_in[12];
    const float* W_ih    = (const float*)d_in[13];
    const float* W_hh    = (const float*)d_in[14];
    const float* b_ih    = (const float*)d_in[15];
    const float* b_hh    = (const float*)d_in[16];
    const float* ln_g    = (const float*)d_in[17];
    const float* ln_b    = (const float*)d_in[18];
    const float* Wm1     = (const float*)d_in[19];
    const float* bm1     = (const float*)d_in[20];
    const float* Wm2     = (const float*)d_in[21];
    const float* bm2     = (const float*)d_in[22];
    float* out = (float*)d_out;
    float* outAttn = out + 65536;   // attn written in place in the final output

    char* ws = (char*)d_ws;
    short* inputs_bf = (short*)ws; ws += 67108864;   // (131072,256) bf16
    short* ksb       = (short*)ws; ws += 33554432;   // (131072,128) bf16
    short* ktb       = (short*)ws; ws += 33554432;
    float* slots     = (float*)ws; ws += 262144;     // (32,8,256) f32
    float* qsb       = (float*)ws; ws += 131072;     // (32,8,128) f32
    float* qtb       = (float*)ws; ws += 131072;
    float* ppart     = (float*)ws; ws += 3145728;    // (1024,768) f32 pool partials
    short* Wp_sw     = (short*)ws; ws += 393216;     // swizzled Wp bf16
    short* Wk_sw     = (short*)ws; ws += 65536;      // swizzled Wks|Wkt bf16
    float* hidb      = (float*)ws; ws += 65536;      // (32,512) f32
    float* Spart     = (float*)ws; ws += 8192;       // (256,8) attn row-sum partials
    float* upart     = (float*)ws; ws += 1048576;    // (4,256,256)

    prep_weights<<<112, 256, 0, stream>>>(Wp, Wks, Wkt, Wp_sw, Wk_sw);
    gemm_in_ln<<<1024, 256, 0, stream>>>(feat, Wp_sw, bp, ln_in_g, ln_in_b, inputs_bf, ppart);
    slots_hid<<<dim3(32, 2), 256, 0, stream>>>(ppart, Wi1, bi1, hidb);
    slots_out<<<256, 256, 0, stream>>>(hidb, Wi2, bi2, slots);
    k_gemm<<<2048, 256, 0, stream>>>(inputs_bf, Wk_sw, ksb, ktb);
    q_proj<<<dim3(32, 2), 256, 0, stream>>>(slots, Wqs, Wqt, qsb, qtb);
    for (int it = 0; it < 3; ++it) {
        attn_kernel<<<dim3(8, 32), 256, 0, stream>>>(ksb, ktb, qsb, qtb, outAttn, Spart);
        updates_kernel<<<256, 256, 0, stream>>>(inputs_bf, outAttn, Spart, upart);
        gru_kernel<<<256, 256, 0, stream>>>(upart, W_ih, W_hh, b_ih, b_hh, ln_g, ln_b,
                                            Wm1, bm1, Wm2, bm2, slots,
                                            Wqs, Wqt, qsb, qtb, out, it == 2 ? 1 : 0);
    }
}

// Round 9
// 1080.609 us; speedup vs baseline: 1.0533x; 1.0533x over previous
//
#include <hip/hip_runtime.h>
#include <math.h>

#define NB 32
#define NN 4096
#define DIN 768
#define DS 256
#define KS 8

typedef short s8v __attribute__((ext_vector_type(8)));
typedef float f4v __attribute__((ext_vector_type(4)));

__device__ __forceinline__ short f2bf(float f) {
    unsigned u = __builtin_bit_cast(unsigned, f);
    u = (u + 0x7FFFu + ((u >> 16) & 1u)) >> 16;
    return (short)u;
}
__device__ __forceinline__ float bf2f(short s) {
    unsigned u = ((unsigned)(unsigned short)s) << 16;
    return __builtin_bit_cast(float, u);
}
__device__ __forceinline__ float gelu_exact(float x) {
    return 0.5f * x * (1.0f + erff(x * 0.70710678118654752f));
}

// ---- swizzle Wp, Wks, Wkt into MFMA B-fragment order (bf16) ----
__global__ __launch_bounds__(256) void prep_weights(const float* Wp, const float* Wks,
                                                    const float* Wkt, short* Wp_sw, short* Wk_sw) {
    int t = blockIdx.x * 256 + threadIdx.x;
    if (t < 24 * 16 * 64) {
        int s = t / (16 * 64), nt = (t / 64) % 16, l = t % 64;
        int q = l >> 4, m = l & 15;
        #pragma unroll
        for (int j = 0; j < 8; ++j)
            Wp_sw[t * 8 + j] = f2bf(Wp[(s * 32 + q * 8 + j) * 256 + nt * 16 + m]);
    } else if (t < 24 * 16 * 64 + 2 * 4 * 8 * 64) {
        int t2 = t - 24 * 16 * 64;
        int half = t2 / (4 * 8 * 64);
        int r = t2 % (4 * 8 * 64);
        int s = r / (8 * 64), nt = (r / 64) % 8, l = r % 64;
        int q = l >> 4, m = l & 15;
        const float* W = half ? Wkt : Wks;
        #pragma unroll
        for (int j = 0; j < 8; ++j)
            Wk_sw[t2 * 8 + j] = f2bf(W[(s * 32 + q * 8 + j) * 128 + nt * 16 + m]);
    }
}

// ---- big GEMM fused with feature pooling: 1024 blocks x 128 rows (R3-proven) ----
__global__ __launch_bounds__(256, 2) void gemm_in_ln(const float* feat, const short* Wp_sw,
                                                     const float* bp, const float* g,
                                                     const float* bb, short* inputs_bf,
                                                     float* ppart) {
    __shared__ short Als[128 * 40];
    __shared__ short Bls[16 * 64 * 8];
    __shared__ float pool_ls[4][768];
    int tid = threadIdx.x;
    int wave = tid >> 6, lane = tid & 63, q = lane >> 4, m = lane & 15;
    long rowblk = (long)blockIdx.x * 128;
    f4v acc[2][16];
    #pragma unroll
    for (int rg = 0; rg < 2; ++rg)
        #pragma unroll
        for (int i = 0; i < 16; ++i) acc[rg][i] = (f4v){0, 0, 0, 0};
    for (int i = tid; i < 4 * 768; i += 256) (&pool_ls[0][0])[i] = 0.0f;
    __syncthreads();
    for (int s = 0; s < 24; ++s) {
        float4 v[4];
        #pragma unroll
        for (int p = 0; p < 4; ++p) {
            int idx = p * 256 + tid;
            int r = idx >> 3, cj = (idx & 7) * 4;
            v[p] = *(const float4*)(feat + (rowblk + r) * 768 + s * 32 + cj);
            short4 pk = make_short4(f2bf(v[p].x), f2bf(v[p].y), f2bf(v[p].z), f2bf(v[p].w));
            *(short4*)&Als[r * 40 + cj] = pk;
        }
        #pragma unroll
        for (int i = 0; i < 4; ++i) {
            int wb = i * 256 + wave * 64;
            __builtin_amdgcn_global_load_lds(
                (const __attribute__((address_space(1))) void*)(Wp_sw + (size_t)s * 8192 +
                                                               (size_t)(wb + lane) * 8),
                (__attribute__((address_space(3))) void*)&Bls[wb * 8], 16, 0, 0);
        }
        __syncthreads();
        {
            float px = v[0].x + v[1].x + v[2].x + v[3].x;
            float py = v[0].y + v[1].y + v[2].y + v[3].y;
            float pz = v[0].z + v[1].z + v[2].z + v[3].z;
            float pw = v[0].w + v[1].w + v[2].w + v[3].w;
            #pragma unroll
            for (int off = 8; off <= 32; off <<= 1) {
                px += __shfl_xor(px, off, 64);
                py += __shfl_xor(py, off, 64);
                pz += __shfl_xor(pz, off, 64);
                pw += __shfl_xor(pw, off, 64);
            }
            if (lane < 8) {
                int col = s * 32 + lane * 4;
                pool_ls[wave][col] += px;
                pool_ls[wave][col + 1] += py;
                pool_ls[wave][col + 2] += pz;
                pool_ls[wave][col + 3] += pw;
            }
        }
        s8v a0 = *(const s8v*)&Als[(wave * 32 + m) * 40 + q * 8];
        s8v a1 = *(const s8v*)&Als[(wave * 32 + 16 + m) * 40 + q * 8];
        #pragma unroll
        for (int nt = 0; nt < 16; ++nt) {
            s8v bf = *(const s8v*)&Bls[(nt * 64 + lane) * 8];
            acc[0][nt] = __builtin_amdgcn_mfma_f32_16x16x32_bf16(a0, bf, acc[0][nt], 0, 0, 0);
            acc[1][nt] = __builtin_amdgcn_mfma_f32_16x16x32_bf16(a1, bf, acc[1][nt], 0, 0, 0);
        }
        __syncthreads();
    }
    #pragma unroll
    for (int rg = 0; rg < 2; ++rg) {
        #pragma unroll
        for (int nt = 0; nt < 16; ++nt) {
            float bpv = bp[nt * 16 + m];
            #pragma unroll
            for (int r = 0; r < 4; ++r) acc[rg][nt][r] += bpv;
        }
        #pragma unroll
        for (int r = 0; r < 4; ++r) {
            float sm = 0, sq = 0;
            #pragma unroll
            for (int nt = 0; nt < 16; ++nt) { float vv = acc[rg][nt][r]; sm += vv; sq += vv * vv; }
            #pragma unroll
            for (int off = 1; off < 16; off <<= 1) {
                sm += __shfl_xor(sm, off, 16);
                sq += __shfl_xor(sq, off, 16);
            }
            float mean = sm * (1.0f / 256.0f);
            float var = sq * (1.0f / 256.0f) - mean * mean;
            float rstd = rsqrtf(var + 1e-5f);
            long grow = rowblk + wave * 32 + rg * 16 + q * 4 + r;
            #pragma unroll
            for (int nt = 0; nt < 16; ++nt) {
                int col = nt * 16 + m;
                float y = (acc[rg][nt][r] - mean) * rstd * g[col] + bb[col];
                inputs_bf[grow * 256 + col] = f2bf(y);
            }
        }
    }
    for (int d = tid; d < 768; d += 256) {
        ppart[(size_t)blockIdx.x * 768 + d] =
            pool_ls[0][d] + pool_ls[1][d] + pool_ls[2][d] + pool_ls[3][d];
    }
}

// ---- slot init MLP stage 1 ----
__global__ __launch_bounds__(256) void slots_hid(const float* ppart, const float* Wi1,
                                                 const float* bi1, float* hidb) {
    __shared__ float pool[768];
    int b = blockIdx.x, half = blockIdx.y, t = threadIdx.x;
    for (int i = 0; i < 3; ++i) {
        int d = t + i * 256;
        float s = 0;
        for (int c = 0; c < 32; ++c) s += ppart[(size_t)(b * 32 + c) * 768 + d];
        pool[d] = s * (1.0f / 4096.0f);
    }
    __syncthreads();
    int c = half * 256 + t;
    float acc = bi1[c];
    for (int j = 0; j < 768; ++j) acc += pool[j] * Wi1[j * 512 + c];
    hidb[b * 512 + c] = gelu_exact(acc);
}

// ---- slot init MLP stage 2 + initial q projection (bit-identical to old q_proj) ----
__global__ __launch_bounds__(256) void slots_out(const float* hidb, const float* Wi2,
                                                 const float* bi2, float* slots,
                                                 const float* Wqs, const float* Wqt,
                                                 float* qs, float* qt) {
    __shared__ float hid[512];
    __shared__ float row[256];
    int b = blockIdx.x >> 3, sl = blockIdx.x & 7, t = threadIdx.x;
    hid[t] = hidb[b * 512 + t];
    hid[256 + t] = hidb[b * 512 + 256 + t];
    __syncthreads();
    int c = sl * 256 + t;
    float acc = bi2[c];
    for (int j = 0; j < 512; ++j) acc += hid[j] * Wi2[j * 2048 + c];
    slots[b * 2048 + c] = acc;
    row[t] = acc;
    __syncthreads();
    int half = t >> 7, d = t & 127;
    const float* W = half ? Wqt : Wqs;
    float qa = 0;
    for (int j = 0; j < 128; ++j) qa += row[half * 128 + j] * W[j * 128 + d];
    (half ? qt : qs)[(b * 8 + sl) * 128 + d] = qa;
}

// ---- k_s / k_t GEMMs (R3-proven) ----
__global__ __launch_bounds__(256) void k_gemm(const short* inputs_bf, const short* Wk_sw,
                                              short* ksb, short* ktb) {
    int tid = threadIdx.x;
    int wave = tid >> 6, lane = tid & 63, q = lane >> 4, m = lane & 15;
    long rowblk = (long)blockIdx.x * 64;
    long arow = rowblk + wave * 16 + m;
    #pragma unroll
    for (int half = 0; half < 2; ++half) {
        f4v acc[8];
        #pragma unroll
        for (int i = 0; i < 8; ++i) acc[i] = (f4v){0, 0, 0, 0};
        const short* wkh = Wk_sw + half * 16384;
        #pragma unroll
        for (int s4 = 0; s4 < 4; ++s4) {
            s8v a = *(const s8v*)(inputs_bf + arow * 256 + half * 128 + s4 * 32 + q * 8);
            #pragma unroll
            for (int nt = 0; nt < 8; ++nt) {
                s8v bf = *(const s8v*)(wkh + ((s4 * 8 + nt) * 64 + lane) * 8);
                acc[nt] = __builtin_amdgcn_mfma_f32_16x16x32_bf16(a, bf, acc[nt], 0, 0, 0);
            }
        }
        short* out = half ? ktb : ksb;
        #pragma unroll
        for (int nt = 0; nt < 8; ++nt)
            #pragma unroll
            for (int r = 0; r < 4; ++r) {
                long grow = rowblk + wave * 16 + q * 4 + r;
                out[grow * 128 + nt * 16 + m] = f2bf(acc[nt][r]);
            }
    }
}

// ---- logits + softmax(axis=k) + per-(b,k) partial N-sums. grid (8,32): 2 n per thread ----
__global__ __launch_bounds__(256) void attn_kernel(const short* ksb, const short* ktb,
                                                   const float* qs, const float* qt,
                                                   float* attn, float* Spart) {
    __shared__ float qls[1024], qlt[1024];
    __shared__ float red[32];
    int ntile = blockIdx.x, b = blockIdx.y, t = threadIdx.x;
    for (int i = 0; i < 4; ++i) {
        int idx = i * 256 + t;
        qls[idx] = qs[b * 1024 + idx];
        qlt[idx] = qt[b * 1024 + idx];
    }
    __syncthreads();
    long n0g = (long)b * 4096 + ntile * 512 + t;
    const short* krs0 = ksb + n0g * 128;
    const short* krt0 = ktb + n0g * 128;
    const short* krs1 = ksb + (n0g + 256) * 128;
    const short* krt1 = ktb + (n0g + 256) * 128;
    float accs0[8] = {0, 0, 0, 0, 0, 0, 0, 0};
    float acct0[8] = {0, 0, 0, 0, 0, 0, 0, 0};
    float accs1[8] = {0, 0, 0, 0, 0, 0, 0, 0};
    float acct1[8] = {0, 0, 0, 0, 0, 0, 0, 0};
    for (int c = 0; c < 16; ++c) {
        s8v vs0 = *(const s8v*)(krs0 + c * 8);
        s8v vt0 = *(const s8v*)(krt0 + c * 8);
        s8v vs1 = *(const s8v*)(krs1 + c * 8);
        s8v vt1 = *(const s8v*)(krt1 + c * 8);
        float fs0[8], ft0[8], fs1[8], ft1[8];
        #pragma unroll
        for (int j = 0; j < 8; ++j) {
            fs0[j] = bf2f(vs0[j]); ft0[j] = bf2f(vt0[j]);
            fs1[j] = bf2f(vs1[j]); ft1[j] = bf2f(vt1[j]);
        }
        #pragma unroll
        for (int k = 0; k < 8; ++k) {
            float as0 = 0, at0 = 0, as1 = 0, at1 = 0;
            #pragma unroll
            for (int j = 0; j < 8; ++j) {
                float qv_s = qls[k * 128 + c * 8 + j];
                float qv_t = qlt[k * 128 + c * 8 + j];
                as0 += qv_s * fs0[j]; as1 += qv_s * fs1[j];
                at0 += qv_t * ft0[j]; at1 += qv_t * ft1[j];
            }
            accs0[k] += as0; acct0[k] += at0;
            accs1[k] += as1; acct1[k] += at1;
        }
    }
    const float cs = 0.7f * 0.08838834764831845f;
    const float ct = 0.3f * 0.08838834764831845f;
    float lg0[8], lg1[8];
    float mx0 = -1e30f, mx1 = -1e30f;
    #pragma unroll
    for (int k = 0; k < 8; ++k) {
        lg0[k] = accs0[k] * cs + acct0[k] * ct; mx0 = fmaxf(mx0, lg0[k]);
        lg1[k] = accs1[k] * cs + acct1[k] * ct; mx1 = fmaxf(mx1, lg1[k]);
    }
    float se0 = 0, se1 = 0;
    #pragma unroll
    for (int k = 0; k < 8; ++k) {
        lg0[k] = expf(lg0[k] - mx0); se0 += lg0[k];
        lg1[k] = expf(lg1[k] - mx1); se1 += lg1[k];
    }
    float inv0 = 1.0f / se0, inv1 = 1.0f / se1;
    int nn0 = ntile * 512 + t;
    #pragma unroll
    for (int k = 0; k < 8; ++k) {
        float a0 = lg0[k] * inv0;
        float a1 = lg1[k] * inv1;
        attn[((long)(b * 8 + k)) * 4096 + nn0] = a0;
        attn[((long)(b * 8 + k)) * 4096 + nn0 + 256] = a1;
        lg0[k] = a0 + a1;
    }
    int lane = t & 63, wv = t >> 6;
    #pragma unroll
    for (int k = 0; k < 8; ++k) {
        float v = lg0[k];
        #pragma unroll
        for (int off = 1; off < 64; off <<= 1) v += __shfl_xor(v, off, 64);
        if (lane == 0) red[wv * 8 + k] = v;
    }
    __syncthreads();
    if (t < 8) {
        float s = red[t] + red[8 + t] + red[16 + t] + red[24 + t];
        Spart[(b * 8 + t) * 8 + ntile] = s;
    }
}

// ---- updates = attn_normed @ inputs (partials over n-quarters). grid 512, 256 thr ----
__global__ __launch_bounds__(256) void updates_kernel(const short* inputs_bf, const float* attn,
                                                      const float* Spart, float* upart) {
    __shared__ unsigned inls[64 * 32];  // 64 n x 64 d as bf16 pairs
    __shared__ float atls[8 * 64];
    int bid = blockIdx.x;
    int b = bid >> 4, dt = (bid >> 2) & 3, nq = bid & 3;
    int t = threadIdx.x;
    int k = t >> 5, dp = t & 31;
    const float* spp = Spart + (b * 8 + k) * 8;
    float sp = ((spp[0] + spp[1]) + (spp[2] + spp[3])) +
               ((spp[4] + spp[5]) + (spp[6] + spp[7]));
    float rk = 1.0f / (sp + 1e-8f);
    float a0 = 0, a1 = 0;
    for (int ch = 0; ch < 16; ++ch) {
        long n0 = nq * 1024 + ch * 64;
        #pragma unroll
        for (int p = 0; p < 2; ++p) {
            int idx = p * 256 + t;
            int rr = idx >> 3, cc = idx & 7;
            *(uint4*)&inls[rr * 32 + cc * 4] =
                *(const uint4*)(inputs_bf + ((long)b * 4096 + n0 + rr) * 256 + dt * 64 + cc * 8);
        }
        {
            int c2 = (t & 31) * 2;
            float2 av = *(const float2*)(attn + ((long)(b * 8 + k)) * 4096 + n0 + c2);
            atls[k * 64 + c2] = av.x * rk;
            atls[k * 64 + c2 + 1] = av.y * rk;
        }
        __syncthreads();
        #pragma unroll
        for (int j = 0; j < 64; ++j) {
            float a = atls[k * 64 + j];
            unsigned u = inls[j * 32 + dp];
            a0 += a * bf2f((short)(u & 0xFFFF));
            a1 += a * bf2f((short)(u >> 16));
        }
        __syncthreads();
    }
    int bk = b * 8 + k;
    upart[((nq * 256 + bk) * 256) + dt * 64 + dp * 2] = a0;
    upart[((nq * 256 + bk) * 256) + dt * 64 + dp * 2 + 1] = a1;
}

// ---- GRU + LN + MLP residual + (next-iter q | final out). grid 256 (b*8+k), 256 thr ----
__global__ __launch_bounds__(256) void gru_kernel(const float* upart, const float* W_ih,
                                                  const float* W_hh, const float* b_ih,
                                                  const float* b_hh, const float* ln_g,
                                                  const float* ln_b, const float* Wm1,
                                                  const float* bm1, const float* Wm2,
                                                  const float* bm2, float* slots,
                                                  const float* Wqs, const float* Wqt,
                                                  float* qs, float* qt, float* out, int final_it) {
    __shared__ float u[256], h[256], sn[256], hid[512];
    __shared__ float redA[4], redB[4];
    int bk = blockIdx.x, t = threadIdx.x;
    u[t] = upart[(0 * 256 + bk) * 256 + t] + upart[(1 * 256 + bk) * 256 + t] +
           upart[(2 * 256 + bk) * 256 + t] + upart[(3 * 256 + bk) * 256 + t];
    h[t] = slots[bk * 256 + t];
    __syncthreads();
    float xr = b_ih[t], xz = b_ih[256 + t], xn = b_ih[512 + t];
    float hr = b_hh[t], hz = b_hh[256 + t], hn = b_hh[512 + t];
    for (int j = 0; j < 256; ++j) {
        float uj = u[j], hj = h[j];
        const float* wi = W_ih + j * 768 + t;
        const float* wh = W_hh + j * 768 + t;
        xr += uj * wi[0]; xz += uj * wi[256]; xn += uj * wi[512];
        hr += hj * wh[0]; hz += hj * wh[256]; hn += hj * wh[512];
    }
    float rg = 1.0f / (1.0f + expf(-(xr + hr)));
    float zg = 1.0f / (1.0f + expf(-(xz + hz)));
    float ng = tanhf(xn + rg * hn);
    float hnew = (1.0f - zg) * ng + zg * h[t];
    float v1 = hnew, v2 = hnew * hnew;
    int lane = t & 63, wv = t >> 6;
    #pragma unroll
    for (int off = 1; off < 64; off <<= 1) {
        v1 += __shfl_xor(v1, off, 64);
        v2 += __shfl_xor(v2, off, 64);
    }
    if (lane == 0) { redA[wv] = v1; redB[wv] = v2; }
    __syncthreads();
    float sm = redA[0] + redA[1] + redA[2] + redA[3];
    float sq = redB[0] + redB[1] + redB[2] + redB[3];
    float mean = sm * (1.0f / 256.0f);
    float var = sq * (1.0f / 256.0f) - mean * mean;
    float rstd = rsqrtf(var + 1e-5f);
    sn[t] = (hnew - mean) * rstd * ln_g[t] + ln_b[t];
    __syncthreads();
    float m1 = bm1[t], m2 = bm1[256 + t];
    for (int j = 0; j < 256; ++j) {
        float s = sn[j];
        m1 += s * Wm1[j * 512 + t];
        m2 += s * Wm1[j * 512 + 256 + t];
    }
    hid[t] = gelu_exact(m1);
    hid[256 + t] = gelu_exact(m2);
    __syncthreads();
    float o = bm2[t];
    for (int j = 0; j < 512; ++j) o += hid[j] * Wm2[j * 256 + t];
    float v = hnew + o;
    slots[bk * 256 + t] = v;
    if (!final_it) {
        u[t] = v;
        __syncthreads();
        int half = t >> 7, d = t & 127;
        const float* W = half ? Wqt : Wqs;
        float qa = 0;
        for (int j = 0; j < 128; ++j) qa += u[half * 128 + j] * W[j * 128 + d];
        (half ? qt : qs)[bk * 128 + d] = qa;
    } else {
        out[bk * 256 + t] = v;
        if (t < 128) out[1114112 + bk * 128 + t] = v;
        else out[1114112 + 32768 + bk * 128 + (t - 128)] = v;
    }
}

extern "C" void kernel_launch(void* const* d_in, const int* in_sizes, int n_in,
                              void* d_out, int out_size, void* d_ws, size_t ws_size,
                              hipStream_t stream) {
    const float* feat    = (const float*)d_in[0];
    const float* Wi1     = (const float*)d_in[1];
    const float* bi1     = (const float*)d_in[2];
    const float* Wi2     = (const float*)d_in[3];
    const float* bi2     = (const float*)d_in[4];
    const float* Wp      = (const float*)d_in[5];
    const float* bp      = (const float*)d_in[6];
    const float* ln_in_g = (const float*)d_in[7];
    const float* ln_in_b = (const float*)d_in[8];
    const float* Wqs     = (const float*)d_in[9];
    const float* Wks     = (const float*)d_in[10];
    const float* Wqt     = (const float*)d_in[11];
    const float* Wkt     = (const float*)d_in[12];
    const float* W_ih    = (const float*)d_in[13];
    const float* W_hh    = (const float*)d_in[14];
    const float* b_ih    = (const float*)d_in[15];
    const float* b_hh    = (const float*)d_in[16];
    const float* ln_g    = (const float*)d_in[17];
    const float* ln_b    = (const float*)d_in[18];
    const float* Wm1     = (const float*)d_in[19];
    const float* bm1     = (const float*)d_in[20];
    const float* Wm2     = (const float*)d_in[21];
    const float* bm2     = (const float*)d_in[22];
    float* out = (float*)d_out;
    float* outAttn = out + 65536;   // attn written in place in the final output

    char* ws = (char*)d_ws;
    short* inputs_bf = (short*)ws; ws += 67108864;   // (131072,256) bf16
    short* ksb       = (short*)ws; ws += 33554432;   // (131072,128) bf16
    short* ktb       = (short*)ws; ws += 33554432;
    float* slots     = (float*)ws; ws += 262144;     // (32,8,256) f32
    float* qsb       = (float*)ws; ws += 131072;     // (32,8,128) f32
    float* qtb       = (float*)ws; ws += 131072;
    float* ppart     = (float*)ws; ws += 3145728;    // (1024,768) f32 pool partials
    short* Wp_sw     = (short*)ws; ws += 393216;     // swizzled Wp bf16
    short* Wk_sw     = (short*)ws; ws += 65536;      // swizzled Wks|Wkt bf16
    float* hidb      = (float*)ws; ws += 65536;      // (32,512) f32
    float* Spart     = (float*)ws; ws += 8192;       // (256,8) attn row-sum partials
    float* upart     = (float*)ws; ws += 1048576;    // (4,256,256)

    prep_weights<<<112, 256, 0, stream>>>(Wp, Wks, Wkt, Wp_sw, Wk_sw);
    gemm_in_ln<<<1024, 256, 0, stream>>>(feat, Wp_sw, bp, ln_in_g, ln_in_b, inputs_bf, ppart);
    slots_hid<<<dim3(32, 2), 256, 0, stream>>>(ppart, Wi1, bi1, hidb);
    slots_out<<<256, 256, 0, stream>>>(hidb, Wi2, bi2, slots, Wqs, Wqt, qsb, qtb);
    k_gemm<<<2048, 256, 0, stream>>>(inputs_bf, Wk_sw, ksb, ktb);
    for (int it = 0; it < 3; ++it) {
        attn_kernel<<<dim3(8, 32), 256, 0, stream>>>(ksb, ktb, qsb, qtb, outAttn, Spart);
        updates_kernel<<<512, 256, 0, stream>>>(inputs_bf, outAttn, Spart, upart);
        gru_kernel<<<256, 256, 0, stream>>>(upart, W_ih, W_hh, b_ih, b_hh, ln_g, ln_b,
                                            Wm1, bm1, Wm2, bm2, slots,
                                            Wqs, Wqt, qsb, qtb, out, it == 2 ? 1 : 0);
    }
}

// Round 10
// 1061.335 us; speedup vs baseline: 1.0724x; 1.0182x over previous
//
#include <hip/hip_runtime.h>
#include <math.h>

#define NB 32
#define NN 4096
#define DIN 768
#define DS 256
#define KS 8

typedef short s8v __attribute__((ext_vector_type(8)));
typedef float f4v __attribute__((ext_vector_type(4)));

__device__ __forceinline__ short f2bf(float f) {
    unsigned u = __builtin_bit_cast(unsigned, f);
    u = (u + 0x7FFFu + ((u >> 16) & 1u)) >> 16;
    return (short)u;
}
__device__ __forceinline__ float bf2f(short s) {
    unsigned u = ((unsigned)(unsigned short)s) << 16;
    return __builtin_bit_cast(float, u);
}
__device__ __forceinline__ float gelu_exact(float x) {
    return 0.5f * x * (1.0f + erff(x * 0.70710678118654752f));
}

// ---- swizzle Wp, Wks, Wkt into MFMA B-fragment order (bf16) ----
__global__ __launch_bounds__(256) void prep_weights(const float* Wp, const float* Wks,
                                                    const float* Wkt, short* Wp_sw, short* Wk_sw) {
    int t = blockIdx.x * 256 + threadIdx.x;
    if (t < 24 * 16 * 64) {
        int s = t / (16 * 64), nt = (t / 64) % 16, l = t % 64;
        int q = l >> 4, m = l & 15;
        #pragma unroll
        for (int j = 0; j < 8; ++j)
            Wp_sw[t * 8 + j] = f2bf(Wp[(s * 32 + q * 8 + j) * 256 + nt * 16 + m]);
    } else if (t < 24 * 16 * 64 + 2 * 4 * 8 * 64) {
        int t2 = t - 24 * 16 * 64;
        int half = t2 / (4 * 8 * 64);
        int r = t2 % (4 * 8 * 64);
        int s = r / (8 * 64), nt = (r / 64) % 8, l = r % 64;
        int q = l >> 4, m = l & 15;
        const float* W = half ? Wkt : Wks;
        #pragma unroll
        for (int j = 0; j < 8; ++j)
            Wk_sw[t2 * 8 + j] = f2bf(W[(s * 32 + q * 8 + j) * 128 + nt * 16 + m]);
    }
}

// ---- big GEMM fused with feature pooling: 1024 blocks x 128 rows (R3-proven) ----
__global__ __launch_bounds__(256, 2) void gemm_in_ln(const float* feat, const short* Wp_sw,
                                                     const float* bp, const float* g,
                                                     const float* bb, short* inputs_bf,
                                                     float* ppart) {
    __shared__ short Als[128 * 40];
    __shared__ short Bls[16 * 64 * 8];
    __shared__ float pool_ls[4][768];
    int tid = threadIdx.x;
    int wave = tid >> 6, lane = tid & 63, q = lane >> 4, m = lane & 15;
    long rowblk = (long)blockIdx.x * 128;
    f4v acc[2][16];
    #pragma unroll
    for (int rg = 0; rg < 2; ++rg)
        #pragma unroll
        for (int i = 0; i < 16; ++i) acc[rg][i] = (f4v){0, 0, 0, 0};
    for (int i = tid; i < 4 * 768; i += 256) (&pool_ls[0][0])[i] = 0.0f;
    __syncthreads();
    for (int s = 0; s < 24; ++s) {
        float4 v[4];
        #pragma unroll
        for (int p = 0; p < 4; ++p) {
            int idx = p * 256 + tid;
            int r = idx >> 3, cj = (idx & 7) * 4;
            v[p] = *(const float4*)(feat + (rowblk + r) * 768 + s * 32 + cj);
            short4 pk = make_short4(f2bf(v[p].x), f2bf(v[p].y), f2bf(v[p].z), f2bf(v[p].w));
            *(short4*)&Als[r * 40 + cj] = pk;
        }
        #pragma unroll
        for (int i = 0; i < 4; ++i) {
            int wb = i * 256 + wave * 64;
            __builtin_amdgcn_global_load_lds(
                (const __attribute__((address_space(1))) void*)(Wp_sw + (size_t)s * 8192 +
                                                               (size_t)(wb + lane) * 8),
                (__attribute__((address_space(3))) void*)&Bls[wb * 8], 16, 0, 0);
        }
        __syncthreads();
        {
            float px = v[0].x + v[1].x + v[2].x + v[3].x;
            float py = v[0].y + v[1].y + v[2].y + v[3].y;
            float pz = v[0].z + v[1].z + v[2].z + v[3].z;
            float pw = v[0].w + v[1].w + v[2].w + v[3].w;
            #pragma unroll
            for (int off = 8; off <= 32; off <<= 1) {
                px += __shfl_xor(px, off, 64);
                py += __shfl_xor(py, off, 64);
                pz += __shfl_xor(pz, off, 64);
                pw += __shfl_xor(pw, off, 64);
            }
            if (lane < 8) {
                int col = s * 32 + lane * 4;
                pool_ls[wave][col] += px;
                pool_ls[wave][col + 1] += py;
                pool_ls[wave][col + 2] += pz;
                pool_ls[wave][col + 3] += pw;
            }
        }
        s8v a0 = *(const s8v*)&Als[(wave * 32 + m) * 40 + q * 8];
        s8v a1 = *(const s8v*)&Als[(wave * 32 + 16 + m) * 40 + q * 8];
        #pragma unroll
        for (int nt = 0; nt < 16; ++nt) {
            s8v bf = *(const s8v*)&Bls[(nt * 64 + lane) * 8];
            acc[0][nt] = __builtin_amdgcn_mfma_f32_16x16x32_bf16(a0, bf, acc[0][nt], 0, 0, 0);
            acc[1][nt] = __builtin_amdgcn_mfma_f32_16x16x32_bf16(a1, bf, acc[1][nt], 0, 0, 0);
        }
        __syncthreads();
    }
    #pragma unroll
    for (int rg = 0; rg < 2; ++rg) {
        #pragma unroll
        for (int nt = 0; nt < 16; ++nt) {
            float bpv = bp[nt * 16 + m];
            #pragma unroll
            for (int r = 0; r < 4; ++r) acc[rg][nt][r] += bpv;
        }
        #pragma unroll
        for (int r = 0; r < 4; ++r) {
            float sm = 0, sq = 0;
            #pragma unroll
            for (int nt = 0; nt < 16; ++nt) { float vv = acc[rg][nt][r]; sm += vv; sq += vv * vv; }
            #pragma unroll
            for (int off = 1; off < 16; off <<= 1) {
                sm += __shfl_xor(sm, off, 16);
                sq += __shfl_xor(sq, off, 16);
            }
            float mean = sm * (1.0f / 256.0f);
            float var = sq * (1.0f / 256.0f) - mean * mean;
            float rstd = rsqrtf(var + 1e-5f);
            long grow = rowblk + wave * 32 + rg * 16 + q * 4 + r;
            #pragma unroll
            for (int nt = 0; nt < 16; ++nt) {
                int col = nt * 16 + m;
                float y = (acc[rg][nt][r] - mean) * rstd * g[col] + bb[col];
                inputs_bf[grow * 256 + col] = f2bf(y);
            }
        }
    }
    for (int d = tid; d < 768; d += 256) {
        ppart[(size_t)blockIdx.x * 768 + d] =
            pool_ls[0][d] + pool_ls[1][d] + pool_ls[2][d] + pool_ls[3][d];
    }
}

// ---- slot init MLP stage 1 ----
__global__ __launch_bounds__(256) void slots_hid(const float* ppart, const float* Wi1,
                                                 const float* bi1, float* hidb) {
    __shared__ float pool[768];
    int b = blockIdx.x, half = blockIdx.y, t = threadIdx.x;
    for (int i = 0; i < 3; ++i) {
        int d = t + i * 256;
        float s = 0;
        for (int c = 0; c < 32; ++c) s += ppart[(size_t)(b * 32 + c) * 768 + d];
        pool[d] = s * (1.0f / 4096.0f);
    }
    __syncthreads();
    int c = half * 256 + t;
    float acc = bi1[c];
    for (int j = 0; j < 768; ++j) acc += pool[j] * Wi1[j * 512 + c];
    hidb[b * 512 + c] = gelu_exact(acc);
}

// ---- slot init MLP stage 2 + initial q projection (bit-identical to old q_proj) ----
__global__ __launch_bounds__(256) void slots_out(const float* hidb, const float* Wi2,
                                                 const float* bi2, float* slots,
                                                 const float* Wqs, const float* Wqt,
                                                 float* qs, float* qt) {
    __shared__ float hid[512];
    __shared__ float row[256];
    int b = blockIdx.x >> 3, sl = blockIdx.x & 7, t = threadIdx.x;
    hid[t] = hidb[b * 512 + t];
    hid[256 + t] = hidb[b * 512 + 256 + t];
    __syncthreads();
    int c = sl * 256 + t;
    float acc = bi2[c];
    for (int j = 0; j < 512; ++j) acc += hid[j] * Wi2[j * 2048 + c];
    slots[b * 2048 + c] = acc;
    row[t] = acc;
    __syncthreads();
    int half = t >> 7, d = t & 127;
    const float* W = half ? Wqt : Wqs;
    float qa = 0;
    for (int j = 0; j < 128; ++j) qa += row[half * 128 + j] * W[j * 128 + d];
    (half ? qt : qs)[(b * 8 + sl) * 128 + d] = qa;
}

// ---- k_s / k_t GEMMs (R3-proven) ----
__global__ __launch_bounds__(256) void k_gemm(const short* inputs_bf, const short* Wk_sw,
                                              short* ksb, short* ktb) {
    int tid = threadIdx.x;
    int wave = tid >> 6, lane = tid & 63, q = lane >> 4, m = lane & 15;
    long rowblk = (long)blockIdx.x * 64;
    long arow = rowblk + wave * 16 + m;
    #pragma unroll
    for (int half = 0; half < 2; ++half) {
        f4v acc[8];
        #pragma unroll
        for (int i = 0; i < 8; ++i) acc[i] = (f4v){0, 0, 0, 0};
        const short* wkh = Wk_sw + half * 16384;
        #pragma unroll
        for (int s4 = 0; s4 < 4; ++s4) {
            s8v a = *(const s8v*)(inputs_bf + arow * 256 + half * 128 + s4 * 32 + q * 8);
            #pragma unroll
            for (int nt = 0; nt < 8; ++nt) {
                s8v bf = *(const s8v*)(wkh + ((s4 * 8 + nt) * 64 + lane) * 8);
                acc[nt] = __builtin_amdgcn_mfma_f32_16x16x32_bf16(a, bf, acc[nt], 0, 0, 0);
            }
        }
        short* out = half ? ktb : ksb;
        #pragma unroll
        for (int nt = 0; nt < 8; ++nt)
            #pragma unroll
            for (int r = 0; r < 4; ++r) {
                long grow = rowblk + wave * 16 + q * 4 + r;
                out[grow * 128 + nt * 16 + m] = f2bf(acc[nt][r]);
            }
    }
}

// ---- logits + softmax(axis=k) + per-(b,k) partial N-sums. grid (8,32): 2 n per thread ----
__global__ __launch_bounds__(256) void attn_kernel(const short* ksb, const short* ktb,
                                                   const float* qs, const float* qt,
                                                   float* attn, float* Spart) {
    __shared__ float qls[1024], qlt[1024];
    __shared__ float red[32];
    int ntile = blockIdx.x, b = blockIdx.y, t = threadIdx.x;
    for (int i = 0; i < 4; ++i) {
        int idx = i * 256 + t;
        qls[idx] = qs[b * 1024 + idx];
        qlt[idx] = qt[b * 1024 + idx];
    }
    __syncthreads();
    long n0g = (long)b * 4096 + ntile * 512 + t;
    const short* krs0 = ksb + n0g * 128;
    const short* krt0 = ktb + n0g * 128;
    const short* krs1 = ksb + (n0g + 256) * 128;
    const short* krt1 = ktb + (n0g + 256) * 128;
    float accs0[8] = {0, 0, 0, 0, 0, 0, 0, 0};
    float acct0[8] = {0, 0, 0, 0, 0, 0, 0, 0};
    float accs1[8] = {0, 0, 0, 0, 0, 0, 0, 0};
    float acct1[8] = {0, 0, 0, 0, 0, 0, 0, 0};
    for (int c = 0; c < 16; ++c) {
        s8v vs0 = *(const s8v*)(krs0 + c * 8);
        s8v vt0 = *(const s8v*)(krt0 + c * 8);
        s8v vs1 = *(const s8v*)(krs1 + c * 8);
        s8v vt1 = *(const s8v*)(krt1 + c * 8);
        float fs0[8], ft0[8], fs1[8], ft1[8];
        #pragma unroll
        for (int j = 0; j < 8; ++j) {
            fs0[j] = bf2f(vs0[j]); ft0[j] = bf2f(vt0[j]);
            fs1[j] = bf2f(vs1[j]); ft1[j] = bf2f(vt1[j]);
        }
        #pragma unroll
        for (int k = 0; k < 8; ++k) {
            float as0 = 0, at0 = 0, as1 = 0, at1 = 0;
            #pragma unroll
            for (int j = 0; j < 8; ++j) {
                float qv_s = qls[k * 128 + c * 8 + j];
                float qv_t = qlt[k * 128 + c * 8 + j];
                as0 += qv_s * fs0[j]; as1 += qv_s * fs1[j];
                at0 += qv_t * ft0[j]; at1 += qv_t * ft1[j];
            }
            accs0[k] += as0; acct0[k] += at0;
            accs1[k] += as1; acct1[k] += at1;
        }
    }
    const float cs = 0.7f * 0.08838834764831845f;
    const float ct = 0.3f * 0.08838834764831845f;
    float lg0[8], lg1[8];
    float mx0 = -1e30f, mx1 = -1e30f;
    #pragma unroll
    for (int k = 0; k < 8; ++k) {
        lg0[k] = accs0[k] * cs + acct0[k] * ct; mx0 = fmaxf(mx0, lg0[k]);
        lg1[k] = accs1[k] * cs + acct1[k] * ct; mx1 = fmaxf(mx1, lg1[k]);
    }
    float se0 = 0, se1 = 0;
    #pragma unroll
    for (int k = 0; k < 8; ++k) {
        lg0[k] = expf(lg0[k] - mx0); se0 += lg0[k];
        lg1[k] = expf(lg1[k] - mx1); se1 += lg1[k];
    }
    float inv0 = 1.0f / se0, inv1 = 1.0f / se1;
    int nn0 = ntile * 512 + t;
    #pragma unroll
    for (int k = 0; k < 8; ++k) {
        float a0 = lg0[k] * inv0;
        float a1 = lg1[k] * inv1;
        attn[((long)(b * 8 + k)) * 4096 + nn0] = a0;
        attn[((long)(b * 8 + k)) * 4096 + nn0 + 256] = a1;
        lg0[k] = a0 + a1;
    }
    int lane = t & 63, wv = t >> 6;
    #pragma unroll
    for (int k = 0; k < 8; ++k) {
        float v = lg0[k];
        #pragma unroll
        for (int off = 1; off < 64; off <<= 1) v += __shfl_xor(v, off, 64);
        if (lane == 0) red[wv * 8 + k] = v;
    }
    __syncthreads();
    if (t < 8) {
        float s = red[t] + red[8 + t] + red[16 + t] + red[24 + t];
        Spart[(b * 8 + t) * 8 + ntile] = s;
    }
}

// ---- updates = attn_normed @ inputs (partials over n-eighths). grid 1024, 256 thr ----
__global__ __launch_bounds__(256) void updates_kernel(const short* inputs_bf, const float* attn,
                                                      const float* Spart, float* upart) {
    __shared__ unsigned inls[64 * 32];  // 64 n x 64 d as bf16 pairs
    __shared__ float atls[8 * 64];
    int bid = blockIdx.x;
    int b = bid >> 5, dt = (bid >> 3) & 3, nq = bid & 7;
    int t = threadIdx.x;
    int k = t >> 5, dp = t & 31;
    const float* spp = Spart + (b * 8 + k) * 8;
    float sp = ((spp[0] + spp[1]) + (spp[2] + spp[3])) +
               ((spp[4] + spp[5]) + (spp[6] + spp[7]));
    float rk = 1.0f / (sp + 1e-8f);
    float a0 = 0, a1 = 0;
    for (int ch = 0; ch < 8; ++ch) {
        long n0 = (long)nq * 512 + ch * 64;
        #pragma unroll
        for (int p = 0; p < 2; ++p) {
            int idx = p * 256 + t;
            int rr = idx >> 3, cc = idx & 7;
            *(uint4*)&inls[rr * 32 + cc * 4] =
                *(const uint4*)(inputs_bf + ((long)b * 4096 + n0 + rr) * 256 + dt * 64 + cc * 8);
        }
        {
            int c2 = (t & 31) * 2;
            float2 av = *(const float2*)(attn + ((long)(b * 8 + k)) * 4096 + n0 + c2);
            atls[k * 64 + c2] = av.x * rk;
            atls[k * 64 + c2 + 1] = av.y * rk;
        }
        __syncthreads();
        #pragma unroll
        for (int j = 0; j < 64; ++j) {
            float a = atls[k * 64 + j];
            unsigned u = inls[j * 32 + dp];
            a0 += a * bf2f((short)(u & 0xFFFF));
            a1 += a * bf2f((short)(u >> 16));
        }
        __syncthreads();
    }
    int bk = b * 8 + k;
    upart[((long)(nq * 256 + bk) * 256) + dt * 64 + dp * 2] = a0;
    upart[((long)(nq * 256 + bk) * 256) + dt * 64 + dp * 2 + 1] = a1;
}

// ---- GRU + LN + MLP residual + (next-iter q | final out). grid 256 (b*8+k), 256 thr ----
__global__ __launch_bounds__(256) void gru_kernel(const float* upart, const float* W_ih,
                                                  const float* W_hh, const float* b_ih,
                                                  const float* b_hh, const float* ln_g,
                                                  const float* ln_b, const float* Wm1,
                                                  const float* bm1, const float* Wm2,
                                                  const float* bm2, float* slots,
                                                  const float* Wqs, const float* Wqt,
                                                  float* qs, float* qt, float* out, int final_it) {
    __shared__ float u[256], h[256], sn[256], hid[512];
    __shared__ float redA[4], redB[4];
    int bk = blockIdx.x, t = threadIdx.x;
    {
        float us = 0;
        #pragma unroll
        for (int nq = 0; nq < 8; ++nq) us += upart[((long)(nq * 256 + bk) * 256) + t];
        u[t] = us;
    }
    h[t] = slots[bk * 256 + t];
    __syncthreads();
    float xr = b_ih[t], xz = b_ih[256 + t], xn = b_ih[512 + t];
    float hr = b_hh[t], hz = b_hh[256 + t], hn = b_hh[512 + t];
    for (int j = 0; j < 256; ++j) {
        float uj = u[j], hj = h[j];
        const float* wi = W_ih + j * 768 + t;
        const float* wh = W_hh + j * 768 + t;
        xr += uj * wi[0]; xz += uj * wi[256]; xn += uj * wi[512];
        hr += hj * wh[0]; hz += hj * wh[256]; hn += hj * wh[512];
    }
    float rg = 1.0f / (1.0f + expf(-(xr + hr)));
    float zg = 1.0f / (1.0f + expf(-(xz + hz)));
    float ng = tanhf(xn + rg * hn);
    float hnew = (1.0f - zg) * ng + zg * h[t];
    float v1 = hnew, v2 = hnew * hnew;
    int lane = t & 63, wv = t >> 6;
    #pragma unroll
    for (int off = 1; off < 64; off <<= 1) {
        v1 += __shfl_xor(v1, off, 64);
        v2 += __shfl_xor(v2, off, 64);
    }
    if (lane == 0) { redA[wv] = v1; redB[wv] = v2; }
    __syncthreads();
    float sm = redA[0] + redA[1] + redA[2] + redA[3];
    float sq = redB[0] + redB[1] + redB[2] + redB[3];
    float mean = sm * (1.0f / 256.0f);
    float var = sq * (1.0f / 256.0f) - mean * mean;
    float rstd = rsqrtf(var + 1e-5f);
    sn[t] = (hnew - mean) * rstd * ln_g[t] + ln_b[t];
    __syncthreads();
    float m1 = bm1[t], m2 = bm1[256 + t];
    for (int j = 0; j < 256; ++j) {
        float s = sn[j];
        m1 += s * Wm1[j * 512 + t];
        m2 += s * Wm1[j * 512 + 256 + t];
    }
    hid[t] = gelu_exact(m1);
    hid[256 + t] = gelu_exact(m2);
    __syncthreads();
    float o = bm2[t];
    for (int j = 0; j < 512; ++j) o += hid[j] * Wm2[j * 256 + t];
    float v = hnew + o;
    slots[bk * 256 + t] = v;
    if (!final_it) {
        u[t] = v;
        __syncthreads();
        int half = t >> 7, d = t & 127;
        const float* W = half ? Wqt : Wqs;
        float qa = 0;
        for (int j = 0; j < 128; ++j) qa += u[half * 128 + j] * W[j * 128 + d];
        (half ? qt : qs)[bk * 128 + d] = qa;
    } else {
        out[bk * 256 + t] = v;
        if (t < 128) out[1114112 + bk * 128 + t] = v;
        else out[1114112 + 32768 + bk * 128 + (t - 128)] = v;
    }
}

extern "C" void kernel_launch(void* const* d_in, const int* in_sizes, int n_in,
                              void* d_out, int out_size, void* d_ws, size_t ws_size,
                              hipStream_t stream) {
    const float* feat    = (const float*)d_in[0];
    const float* Wi1     = (const float*)d_in[1];
    const float* bi1     = (const float*)d_in[2];
    const float* Wi2     = (const float*)d_in[3];
    const float* bi2     = (const float*)d_in[4];
    const float* Wp      = (const float*)d_in[5];
    const float* bp      = (const float*)d_in[6];
    const float* ln_in_g = (const float*)d_in[7];
    const float* ln_in_b = (const float*)d_in[8];
    const float* Wqs     = (const float*)d_in[9];
    const float* Wks     = (const float*)d_in[10];
    const float* Wqt     = (const float*)d_in[11];
    const float* Wkt     = (const float*)d_in[12];
    const float* W_ih    = (const float*)d_in[13];
    const float* W_hh    = (const float*)d_in[14];
    const float* b_ih    = (const float*)d_in[15];
    const float* b_hh    = (const float*)d_in[16];
    const float* ln_g    = (const float*)d_in[17];
    const float* ln_b    = (const float*)d_in[18];
    const float* Wm1     = (const float*)d_in[19];
    const float* bm1     = (const float*)d_in[20];
    const float* Wm2     = (const float*)d_in[21];
    const float* bm2     = (const float*)d_in[22];
    float* out = (float*)d_out;
    float* outAttn = out + 65536;   // attn written in place in the final output

    char* ws = (char*)d_ws;
    short* inputs_bf = (short*)ws; ws += 67108864;   // (131072,256) bf16
    short* ksb       = (short*)ws; ws += 33554432;   // (131072,128) bf16
    short* ktb       = (short*)ws; ws += 33554432;
    float* slots     = (float*)ws; ws += 262144;     // (32,8,256) f32
    float* qsb       = (float*)ws; ws += 131072;     // (32,8,128) f32
    float* qtb       = (float*)ws; ws += 131072;
    float* ppart     = (float*)ws; ws += 3145728;    // (1024,768) f32 pool partials
    short* Wp_sw     = (short*)ws; ws += 393216;     // swizzled Wp bf16
    short* Wk_sw     = (short*)ws; ws += 65536;      // swizzled Wks|Wkt bf16
    float* hidb      = (float*)ws; ws += 65536;      // (32,512) f32
    float* Spart     = (float*)ws; ws += 8192;       // (256,8) attn row-sum partials
    float* upart     = (float*)ws; ws += 2097152;    // (8,256,256) f32 update partials

    prep_weights<<<112, 256, 0, stream>>>(Wp, Wks, Wkt, Wp_sw, Wk_sw);
    gemm_in_ln<<<1024, 256, 0, stream>>>(feat, Wp_sw, bp, ln_in_g, ln_in_b, inputs_bf, ppart);
    slots_hid<<<dim3(32, 2), 256, 0, stream>>>(ppart, Wi1, bi1, hidb);
    slots_out<<<256, 256, 0, stream>>>(hidb, Wi2, bi2, slots, Wqs, Wqt, qsb, qtb);
    k_gemm<<<2048, 256, 0, stream>>>(inputs_bf, Wk_sw, ksb, ktb);
    for (int it = 0; it < 3; ++it) {
        attn_kernel<<<dim3(8, 32), 256, 0, stream>>>(ksb, ktb, qsb, qtb, outAttn, Spart);
        updates_kernel<<<1024, 256, 0, stream>>>(inputs_bf, outAttn, Spart, upart);
        gru_kernel<<<256, 256, 0, stream>>>(upart, W_ih, W_hh, b_ih, b_hh, ln_g, ln_b,
                                            Wm1, bm1, Wm2, bm2, slots,
                                            Wqs, Wqt, qsb, qtb, out, it == 2 ? 1 : 0);
    }
}